// Round 17
// baseline (1047.757 us; speedup 1.0000x reference)
//
#include <hip/hip_runtime.h>
#include <hip/hip_bf16.h>
#include <hip/hip_fp16.h>

#define NN 50000
#define NNP 50048          // padded node count (782 * 64)
#define EE 800000
#define BB 1000
#define NB 2048            // radial table bins over [0, RTMAX]
#define RTMAX 10.0f
#define WPB 4              // waves per block in agg; each wave owns 2 nodes

typedef _Float16 half8 __attribute__((ext_vector_type(8)));
typedef float floatx4 __attribute__((ext_vector_type(4)));

__device__ __forceinline__ float silu(float x){ return x / (1.0f + __expf(-x)); }

// Internal channel layout (permuted vs reference):
//   scalar: ch j          = j            (j<64)
//   vector: ch 64+32d+j   = v[j][d]      (j<32, d<3)
//   tensor: ch 160+16e+j  = t[j][e]      (j<16, e<5)
// h stored f32 [NNP][256]; channels 240..255 stay zero (K-pad for MFMA).

// ---------------- prep_a: zero deg + wpc + s*Tp ----------------
__global__ __launch_bounds__(256) void prep_a(
    const float* __restrict__ wp0, const float* __restrict__ wp1, const float* __restrict__ wp2,
    const float* __restrict__ s0, const float* __restrict__ s1, const float* __restrict__ s2,
    float* __restrict__ wpc, float* __restrict__ s0Tp, float* __restrict__ s1Tp,
    float* __restrict__ s2Tp, int* __restrict__ deg)
{
    int t = blockIdx.x * 256 + threadIdx.x;
    if (t < NN) deg[t] = 0;
    if (t < 4*64*112) {
        int L = t / (64*112); int r = t % (64*112); int k = r / 112; int j = r % 112;
        float w;
        if (j < 64)      w = wp0[L*64*64 + k*64 + j];
        else if (j < 96) w = wp1[L*64*32 + k*32 + (j-64)];
        else             w = wp2[L*64*16 + k*16 + (j-96)];
        wpc[t] = w;
    }
    if (t < 4*64*72) {
        int L = t / 4608; int r = t % 4608; int j = r / 72; int k = r % 72;
        s0Tp[t] = (k < 64) ? s0[L*4096 + k*64 + j] : 0.0f;
    }
    if (t < 4*32*40) {
        int L = t / 1280; int r = t % 1280; int j = r / 40; int k = r % 40;
        s1Tp[t] = (k < 32) ? s1[L*1024 + k*32 + j] : 0.0f;
    }
    if (t < 4*16*40) {
        int L = t / 640; int r = t % 640; int j = r / 40; int k = r % 40;
        s2Tp[t] = (k < 16) ? s2[L*256 + k*16 + j] : 0.0f;
    }
}

// ---------------- prep_b: wpTp + pt ----------------
__global__ __launch_bounds__(256) void prep_b(
    const float* __restrict__ wpc, const float* __restrict__ emb,
    float* __restrict__ wpTp, float* __restrict__ pt)
{
    int t = blockIdx.x*256 + threadIdx.x;
    if (t < 4*112*72) {
        int L = t / 8064; int r = t % 8064; int m = r / 72; int k = r % 72;
        wpTp[t] = (k < 64) ? wpc[L*7168 + k*112 + m] : 0.0f;
    }
    if (t < 100*112) {
        int zz = t / 112, j = t % 112;
        float s = 0.0f;
        #pragma unroll 8
        for (int k = 0; k < 64; k++) s += emb[zz*64 + k] * wpc[k*112 + j];
        pt[t] = s;
    }
}

// ---------------- CSR build ----------------
__global__ __launch_bounds__(256) void hist_kernel(const int* __restrict__ ei, int* __restrict__ deg)
{
    int e = blockIdx.x * 256 + threadIdx.x;
    if (e < EE) atomicAdd(&deg[ei[EE + e]], 1);
}

__global__ __launch_bounds__(256) void scan1(const int* __restrict__ deg,
                                             int* __restrict__ start, int* __restrict__ bsum)
{
    __shared__ int buf[256];
    int tid = threadIdx.x;
    int i = blockIdx.x*256 + tid;
    int v = (i < NN) ? deg[i] : 0;
    buf[tid] = v; __syncthreads();
    #pragma unroll
    for (int off = 1; off < 256; off <<= 1) {
        int t = (tid >= off) ? buf[tid-off] : 0;
        __syncthreads(); buf[tid] += t; __syncthreads();
    }
    if (i < NN) start[i] = buf[tid] - v;
    if (tid == 255) bsum[blockIdx.x] = buf[255];
}
__global__ __launch_bounds__(256) void scan2(int* __restrict__ bsum, int nb)
{
    __shared__ int buf[256];
    int tid = threadIdx.x;
    int v = (tid < nb) ? bsum[tid] : 0;
    buf[tid] = v; __syncthreads();
    #pragma unroll
    for (int off = 1; off < 256; off <<= 1) {
        int t = (tid >= off) ? buf[tid-off] : 0;
        __syncthreads(); buf[tid] += t; __syncthreads();
    }
    if (tid < nb) bsum[tid] = buf[tid] - v;
}
__global__ __launch_bounds__(256) void scan3(int* __restrict__ start, const int* __restrict__ bsum,
                                             int* __restrict__ cursor)
{
    int i = blockIdx.x*256 + threadIdx.x;
    if (i < NN) { int v = start[i] + bsum[blockIdx.x]; start[i] = v; cursor[i] = v; }
    if (i == 0) start[NN] = EE;
}

// ---------------- fused geometry + scatter: 16B packed edge record ----------------
__global__ __launch_bounds__(256) void geom_scatter(
    const float* __restrict__ pos, const int* __restrict__ ei, const float* __restrict__ shift,
    int* __restrict__ cursor, int4* __restrict__ edata)
{
    int e = blockIdx.x * 256 + threadIdx.x;
    if (e >= EE) return;
    int s = ei[e], d = ei[EE + e];
    float vx = pos[d*3+0] - pos[s*3+0] + shift[e*3+0];
    float vy = pos[d*3+1] - pos[s*3+1] + shift[e*3+1];
    float vz = pos[d*3+2] - pos[s*3+2] + shift[e*3+2];
    float r = sqrtf(vx*vx + vy*vy + vz*vz);
    float inv = 1.0f / (r + 1e-9f);
    float x = vx*inv, y = vy*inv, z = vz*inv;
    int p = atomicAdd(&cursor[d], 1);
    __half2 xy = __floats2half2_rn(x, y);
    __half2 z0 = __floats2half2_rn(z, 0.0f);
    int4 rec;
    rec.x = s;
    rec.y = __float_as_int(r);
    rec.z = *(const int*)&xy;
    rec.w = *(const int*)&z0;
    edata[p] = rec;
}

// ---------------- radial features on the bin grid (f32, NB+1 bins) ----------------
__global__ __launch_bounds__(128) void build_rf(
    const float* __restrict__ rw1, const float* __restrict__ rb1,
    const float* __restrict__ rw2, const float* __restrict__ rb2,
    float* __restrict__ rfall)
{
    int idx = blockIdx.x;
    int L = idx / (NB+1), bin = idx % (NB+1);
    float r = bin * (RTMAX / NB);
    int t = threadIdx.x;
    __shared__ float h1[64];
    if (t < 64) {
        float s = rb1[L*64 + t];
        #pragma unroll
        for (int i = 0; i < 10; i++) { float a = 1.8f*r - (float)i; s += __expf(-a*a) * rw1[L*640 + i*64 + t]; }
        h1[t] = silu(s);
    }
    __syncthreads();
    if (t < 112) {
        float s = rb2[L*112 + t];
        #pragma unroll 8
        for (int k = 0; k < 64; k++) s += h1[k] * rw2[(size_t)L*7168 + k*112 + t];
        rfall[(size_t)idx*112 + t] = s * 0.25f;
    }
}

// pack (delta form): tabpack[L][bin][lane] = { half2(A_base,A_delta), half2(B_base,B_delta) }
__global__ __launch_bounds__(256) void pack_tab(
    const float* __restrict__ rfall, uint2* __restrict__ tabpack)
{
    int t = blockIdx.x*256 + threadIdx.x;
    if (t >= 4*NB*64) return;
    int lane = t & 63;
    int rest = t >> 6;
    int L = rest / NB, bin = rest % NB;
    const float* lo = rfall + (size_t)(L*(NB+1) + bin)*112;
    const float* hi = lo + 112;
    float aLo = lo[lane], aHi = hi[lane];
    float bLo = (lane < 48) ? lo[64+lane] : 0.0f;
    float bHi = (lane < 48) ? hi[64+lane] : 0.0f;
    __half2 ha = __floats2half2_rn(aLo, aHi - aLo);
    __half2 hb = __floats2half2_rn(bLo, bHi - bLo);
    uint2 o;
    o.x = *(const unsigned*)&ha;
    o.y = *(const unsigned*)&hb;
    tabpack[t] = o;
}

// ---------------- init: h f32 [NNP][256] + packed P0 + zero pad row NN ----------------
__global__ __launch_bounds__(256) void init_hp32(
    const int* __restrict__ z, const float* __restrict__ emb,
    const float* __restrict__ pt, float* __restrict__ hG,
    unsigned* __restrict__ Pa, unsigned* __restrict__ Pb)
{
    int n = blockIdx.x; int j = threadIdx.x;
    int zz = z[n];
    hG[(size_t)n*256 + j] = (j < 64) ? emb[zz*64 + j] : 0.0f;
    if (j < 64) {
        float a = pt[zz*112 + j];
        float b = (j < 48) ? pt[zz*112 + 64 + j] : 0.0f;
        __half2 hp = __floats2half2_rn(a, b);
        Pa[(size_t)n*64 + j] = *(const unsigned*)&hp;
    }
    if (n == 0 && j < 64) {          // zero "dummy" row NN (target of invalid-lane gathers)
        Pa[(size_t)NN*64 + j] = 0u;
        Pb[(size_t)NN*64 + j] = 0u;
    }
}

// ---------------- aggregation: 2 nodes/wave; branch-free fully-unrolled consume ----------------
// edge row: [boff, poff, fr, sh7 | sh0, sh1, sh2, 0 | sh3, sh4, sh5, sh6]
// invalid lanes decode with poff -> zero row NN => contributions vanish, no guards.
__global__ __launch_bounds__(256) void agg_kernel(
    const unsigned* __restrict__ Ppack, const int4* __restrict__ edata,
    const int* __restrict__ start, const uint2* __restrict__ tabp,
    float* __restrict__ acc)
{
    int lane = threadIdx.x & 63;
    int wv   = threadIdx.x >> 6;
    int nA = blockIdx.x*(WPB*2) + wv*2;
    int nB = nA + 1;

    __shared__ float ebuf_s[WPB][2][16*12];
    __shared__ float accb_s[WPB][2][240];

    int p0A = start[nA], p1A = start[nA+1];
    int p1B = start[nB+1];
    float aS_A = 0.0f, aS_B = 0.0f;
    float aB_A[5] = {0,0,0,0,0};
    float aB_B[5] = {0,0,0,0,0};
    bool hasB = lane < 48;
    bool isT  = lane >= 32;
    int shqoff = isT ? 8 : 4;
    const float binscale = (float)NB / RTMAX;
    const float C3 = 1.7320508075688772f, C15 = 3.872983346207417f, C5 = 2.23606797749979f;

    const char* tabc = (const char*)tabp;
    const char* Pc   = (const char*)Ppack;
    int lane8 = lane*8, lane4 = lane*4;

    int baseA = p0A, baseB = p1A;
    while (baseA < p1A || baseB < p1B) {
        int cntA = p1A - baseA; cntA = cntA < 0 ? 0 : (cntA > 16 ? 16 : cntA);
        int cntB = p1B - baseB; cntB = cntB < 0 ? 0 : (cntB > 16 ? 16 : cntB);
        // decode: ALL 16 lanes write a row; invalid lanes point P at the zero row
        #pragma unroll
        for (int s = 0; s < 2; s++) {
            int cnt  = s ? cntB : cntA;
            int base = s ? baseB : baseA;
            if (lane < 16) {
                int pos = base + lane; if (pos > p1B-1) pos = p1B-1; if (pos < 0) pos = 0;
                int4 rec = edata[pos];
                int poff = (lane < cnt) ? rec.x*256 : NN*256;
                float f = fminf(__int_as_float(rec.y) * binscale, (float)NB - 0.5f);
                int b = (int)f;
                float fr = f - (float)b;
                __half2 xy = *(const __half2*)&rec.z;
                __half2 z0 = *(const __half2*)&rec.w;
                float x = __half2float(xy.x), y = __half2float(xy.y), z = __half2float(z0.x);
                float4* v4 = (float4*)(ebuf_s[wv][s] + lane*12);
                v4[0] = make_float4(__int_as_float(b*512), __int_as_float(poff), fr,
                                    0.5f*C15*(x*x - y*y));
                v4[1] = make_float4(C3*x, C3*y, C3*z, 0.0f);
                v4[2] = make_float4(C15*x*y, C15*y*z, 0.5f*C5*(3.0f*z*z - 1.0f), C15*x*z);
            }
        }
        asm volatile("s_waitcnt lgkmcnt(0)" ::: "memory");
        // consume: branch-free, all 32 gathers per stream issued before use
        #pragma unroll
        for (int s = 0; s < 2; s++) {
            const float* eb = ebuf_s[wv][s];
            uint2 tt[16]; unsigned pv[16]; float frv[16]; float s7[16];
            #pragma unroll
            for (int e = 0; e < 16; e++) {
                float4 md = *(const float4*)(eb + e*12);
                frv[e] = md.z; s7[e] = md.w;
                tt[e] = *(const uint2*)(tabc + __float_as_int(md.x) + lane8);
                pv[e] = *(const unsigned*)(Pc + __float_as_int(md.y) + lane4);
            }
            float aS_l = 0.0f;
            float aB_l[5] = {0,0,0,0,0};
            #pragma unroll
            for (int e = 0; e < 16; e++) {
                __half2 ha = *(const __half2*)&tt[e].x;
                __half2 hp = *(const __half2*)&pv[e];
                float fr = frv[e];
                float rfA = __half2float(ha.x) + __half2float(ha.y)*fr;
                aS_l += rfA * __half2float(hp.x);
                if (hasB) {
                    float4 sq = *(const float4*)(eb + e*12 + shqoff);
                    __half2 hb = *(const __half2*)&tt[e].y;
                    float rfB = __half2float(hb.x) + __half2float(hb.y)*fr;
                    float msg = rfB * __half2float(hp.y);
                    aB_l[0] += msg * sq.x;
                    aB_l[1] += msg * sq.y;
                    aB_l[2] += msg * sq.z;
                    if (isT) { aB_l[3] += msg * sq.w; aB_l[4] += msg * s7[e]; }
                }
            }
            if (s == 0) {
                aS_A += aS_l;
                #pragma unroll
                for (int d = 0; d < 5; d++) aB_A[d] += aB_l[d];
            } else {
                aS_B += aS_l;
                #pragma unroll
                for (int d = 0; d < 5; d++) aB_B[d] += aB_l[d];
            }
        }
        asm volatile("s_waitcnt lgkmcnt(0)" ::: "memory");
        baseA += 16; baseB += 16;
    }

    // stage into LDS in PERMUTED channel layout
    #pragma unroll
    for (int s = 0; s < 2; s++) {
        float* ab = accb_s[wv][s];
        ab[lane] = s ? aS_B : aS_A;
        const float* aB = s ? aB_B : aB_A;
        if (lane < 32) {
            #pragma unroll
            for (int d = 0; d < 3; d++) ab[64 + 32*d + lane] = aB[d];
        } else if (lane < 48) {
            #pragma unroll
            for (int d = 0; d < 5; d++) ab[160 + 16*d + (lane-32)] = aB[d];
        }
    }
    asm volatile("s_waitcnt lgkmcnt(0)" ::: "memory");
    #pragma unroll
    for (int s = 0; s < 2; s++) {
        float* arow = acc + (size_t)(nA + s)*240;
        const float* ab = accb_s[wv][s];
        #pragma unroll
        for (int c = lane; c < 240; c += 64) arow[c] = ab[c];
    }
}

// ---------------- MFMA node update + projection (h stays f32) ----------------
__global__ __launch_bounds__(256) void update_kernel(
    float* __restrict__ hG, const float* __restrict__ acc,
    const float* __restrict__ s0Tp, const float* __restrict__ s1Tp, const float* __restrict__ s2Tp,
    const float* __restrict__ wpTp, unsigned* __restrict__ Pnext, int hasNext)
{
    __shared__ _Float16 w0[64*72];
    __shared__ _Float16 w1[32*40];
    __shared__ _Float16 w2[16*40];
    __shared__ _Float16 wpl[112*72];
    __shared__ _Float16 sn[64*72];
    __shared__ _Float16 pbuf[64*120];

    int tid = threadIdx.x;
    int lane = tid & 63, wv = tid >> 6;
    int m = lane & 15, quad = lane >> 4;
    int nblk0 = blockIdx.x * 64;
    int n0 = nblk0 + wv*16;

    for (int i = tid; i < 64*72; i += 256) w0[i] = (_Float16)s0Tp[i];
    for (int i = tid; i < 32*40; i += 256) w1[i] = (_Float16)s1Tp[i];
    for (int i = tid; i < 16*40; i += 256) w2[i] = (_Float16)s2Tp[i];
    for (int i = tid; i < 112*72; i += 256) wpl[i] = (_Float16)wpTp[i];
    __syncthreads();

    size_t hrowm = (size_t)(n0 + m)*256;
    size_t arow0 = (size_t)(n0 + quad*4)*240;
    size_t orow0 = (size_t)(n0 + quad*4)*256;

#define LD8(OFF) ({ \
        float4 v0_ = *(const float4*)(hG + (OFF)); \
        float4 v1_ = *(const float4*)(hG + (OFF) + 4); \
        half8 h_; \
        h_[0] = (_Float16)v0_.x; h_[1] = (_Float16)v0_.y; \
        h_[2] = (_Float16)v0_.z; h_[3] = (_Float16)v0_.w; \
        h_[4] = (_Float16)v1_.x; h_[5] = (_Float16)v1_.y; \
        h_[6] = (_Float16)v1_.z; h_[7] = (_Float16)v1_.w; h_; })

    // ---- GEMM0: scalar block (cols 0..63, K 0..63) ----
    {
        half8 a0 = LD8(hrowm + 0  + quad*8);
        half8 a1 = LD8(hrowm + 32 + quad*8);
        #pragma unroll
        for (int t = 0; t < 4; t++) {
            int cb = 16*t;
            floatx4 c;
            #pragma unroll
            for (int r = 0; r < 4; r++) c[r] = acc[arow0 + (size_t)r*240 + cb + m];
            c = __builtin_amdgcn_mfma_f32_16x16x32_f16(a0, *(const half8*)&w0[(cb+m)*72 + 0  + quad*8], c, 0, 0, 0);
            c = __builtin_amdgcn_mfma_f32_16x16x32_f16(a1, *(const half8*)&w0[(cb+m)*72 + 32 + quad*8], c, 0, 0, 0);
            #pragma unroll
            for (int r = 0; r < 4; r++) {
                float u = silu(c[r]);
                hG[orow0 + (size_t)r*256 + cb + m] = u;
                sn[(wv*16 + quad*4 + r)*72 + cb + m] = (_Float16)u;
            }
        }
    }
    // ---- GEMM1: vector blocks d=0..2 ----
    #pragma unroll
    for (int d = 0; d < 3; d++) {
        int kb = 64 + 32*d;
        half8 av = LD8(hrowm + kb + quad*8);
        #pragma unroll
        for (int t = 0; t < 2; t++) {
            int cb = kb + 16*t;
            floatx4 c;
            #pragma unroll
            for (int r = 0; r < 4; r++) c[r] = acc[arow0 + (size_t)r*240 + cb + m];
            c = __builtin_amdgcn_mfma_f32_16x16x32_f16(av, *(const half8*)&w1[(16*t+m)*40 + quad*8], c, 0, 0, 0);
            #pragma unroll
            for (int r = 0; r < 4; r++) hG[orow0 + (size_t)r*256 + cb + m] = c[r];
        }
    }
    // ---- GEMM2: tensor blocks e=0..4 ----
    #pragma unroll
    for (int e = 0; e < 5; e++) {
        int kb = 160 + 16*e;
        half8 at_ = LD8(hrowm + kb + quad*8);
        floatx4 c;
        #pragma unroll
        for (int r = 0; r < 4; r++) c[r] = acc[arow0 + (size_t)r*240 + kb + m];
        c = __builtin_amdgcn_mfma_f32_16x16x32_f16(at_, *(const half8*)&w2[m*40 + quad*8], c, 0, 0, 0);
        #pragma unroll
        for (int r = 0; r < 4; r++) hG[orow0 + (size_t)r*256 + kb + m] = c[r];
    }

    // ---- projection P = s_new @ wpc_next ----
    if (hasNext) {
        asm volatile("s_waitcnt lgkmcnt(0)" ::: "memory");
        half8 p0 = *(const half8*)&sn[(wv*16 + m)*72 + 0  + quad*8];
        half8 p1 = *(const half8*)&sn[(wv*16 + m)*72 + 32 + quad*8];
        #pragma unroll
        for (int t = 0; t < 7; t++) {
            floatx4 c = {0.0f, 0.0f, 0.0f, 0.0f};
            c = __builtin_amdgcn_mfma_f32_16x16x32_f16(p0, *(const half8*)&wpl[(16*t+m)*72 + 0  + quad*8], c, 0, 0, 0);
            c = __builtin_amdgcn_mfma_f32_16x16x32_f16(p1, *(const half8*)&wpl[(16*t+m)*72 + 32 + quad*8], c, 0, 0, 0);
            #pragma unroll
            for (int r = 0; r < 4; r++) pbuf[(wv*16 + quad*4 + r)*120 + 16*t + m] = (_Float16)c[r];
        }
        __syncthreads();
        for (int i = tid; i < 64*64; i += 256) {
            int node = i >> 6, j = i & 63;
            _Float16 aa = pbuf[node*120 + j];
            _Float16 bb = (j < 48) ? pbuf[node*120 + 64 + j] : (_Float16)0.0f;
            unsigned lo = *(const unsigned short*)&aa;
            unsigned hi = *(const unsigned short*)&bb;
            if (nblk0 + node < NN) Pnext[(size_t)(nblk0 + node)*64 + j] = lo | (hi << 16);
        }
    }
#undef LD8
}

// ---------------- merged readout A+B ----------------
__global__ __launch_bounds__(64) void readout_ab(
    const float* __restrict__ hG, const float* __restrict__ wq, const float* __restrict__ wk,
    const float* __restrict__ wv, float* __restrict__ zr)
{
    int b = blockIdx.x; int j = threadIdx.x;
    int na = 50 * b;
    const float* hr = hG + (size_t)na*256;
    __shared__ float sa[64], qv[64], kqv[64];
    __shared__ float hblk[64][51];
    __shared__ float at[64], hbar[64];
    sa[j] = hr[j];
    if (j < 50) {
        const float* hrr = hG + (size_t)(50*b + j)*256;
        #pragma unroll 8
        for (int k = 0; k < 64; k++) hblk[k][j] = hrr[k];
    }
    __syncthreads();
    float q = 0.0f;
    #pragma unroll 8
    for (int k = 0; k < 64; k++) q += sa[k] * wq[k*64 + j];
    qv[j] = q;
    zr[b*176 + j] = sa[j];
    if (j < 32) {
        float nv = 0.0f;
        #pragma unroll
        for (int c = 0; c < 3; c++) { float v = hr[64 + 32*c + j]; nv += v*v; }
        zr[b*176 + 128 + j] = nv;
    }
    if (j < 16) {
        float nt = 0.0f;
        #pragma unroll
        for (int c = 0; c < 5; c++) { float v = hr[160 + 16*c + j]; nt += v*v; }
        zr[b*176 + 160 + j] = nt;
    }
    __syncthreads();
    float s = 0.0f;
    #pragma unroll 8
    for (int jj = 0; jj < 64; jj++) s += wk[j*64 + jj] * qv[jj];
    kqv[j] = s;
    __syncthreads();
    float logit = -1e30f;
    if (j < 50) {
        float t = 0.0f;
        #pragma unroll 8
        for (int k = 0; k < 64; k++) t += hblk[k][j] * kqv[k];
        logit = t * 0.125f;
    }
    float mx = logit;
    for (int o = 32; o; o >>= 1) mx = fmaxf(mx, __shfl_xor(mx, o));
    float ex = (j < 50) ? __expf(logit - mx) : 0.0f;
    float den = ex;
    for (int o = 32; o; o >>= 1) den += __shfl_xor(den, o);
    at[j] = ex / den;
    __syncthreads();
    float hb = 0.0f;
    #pragma unroll 1
    for (int i = 0; i < 50; i++) hb += at[i] * hblk[j][i];
    hbar[j] = hb;
    __syncthreads();
    float c = 0.0f;
    #pragma unroll 8
    for (int k = 0; k < 64; k++) c += hbar[k] * wv[k*64 + j];
    zr[b*176 + 64 + j] = c;
}

// ---------------- readout C ----------------
__global__ __launch_bounds__(128) void readout_c(
    const float* __restrict__ zr, const float* __restrict__ m1, const float* __restrict__ mb1,
    const float* __restrict__ m2, const float* __restrict__ mb2, float* __restrict__ out)
{
    int b = blockIdx.x; int j = threadIdx.x;
    __shared__ float z[176], tb[128];
    for (int t = j; t < 176; t += 128) z[t] = zr[b*176 + t];
    __syncthreads();
    float a = mb1[j];
    #pragma unroll 8
    for (int k = 0; k < 176; k++) a += z[k] * m1[k*128 + j];
    tb[j] = silu(a);
    __syncthreads();
    float o = mb2[j];
    #pragma unroll 8
    for (int k = 0; k < 128; k++) o += tb[k] * m2[k*128 + j];
    out[b*128 + j] = o;
}

extern "C" void kernel_launch(void* const* d_in, const int* in_sizes, int n_in,
                              void* d_out, int out_size, void* d_ws, size_t ws_size,
                              hipStream_t stream)
{
    const int*   z     = (const int*)  d_in[0];
    const float* pos   = (const float*)d_in[1];
    const int*   ei    = (const int*)  d_in[2];
    const float* shift = (const float*)d_in[3];
    const float* emb = (const float*)d_in[6];
    const float* rw1 = (const float*)d_in[7];
    const float* rb1 = (const float*)d_in[8];
    const float* rw2 = (const float*)d_in[9];
    const float* rb2 = (const float*)d_in[10];
    const float* wp0 = (const float*)d_in[11];
    const float* wp1 = (const float*)d_in[12];
    const float* wp2 = (const float*)d_in[13];
    const float* s0  = (const float*)d_in[14];
    const float* s1  = (const float*)d_in[15];
    const float* s2  = (const float*)d_in[16];
    const float* wq  = (const float*)d_in[17];
    const float* wk  = (const float*)d_in[18];
    const float* wv  = (const float*)d_in[19];
    const float* m1  = (const float*)d_in[20];
    const float* mb1 = (const float*)d_in[21];
    const float* m2  = (const float*)d_in[22];
    const float* mb2 = (const float*)d_in[23];

    float* ws = (float*)d_ws;
    size_t off = 0;
    int4*  edata = (int4*)(ws + off); off += (size_t)4*EE;
    int*   deg    = (int*)(ws + off); off += NN;
    int*   startA = (int*)(ws + off); off += NN + 4;
    int*   cursor = (int*)(ws + off); off += NN;
    int*   bsum   = (int*)(ws + off); off += 256;
    float* hG  = ws + off; off += (size_t)NNP*256;   // f32 [NNP][256]
    float* acc = ws + off; off += (size_t)NNP*240;
    unsigned* Pa = (unsigned*)(ws + off); off += (size_t)NNP*64;
    unsigned* Pb = (unsigned*)(ws + off); off += (size_t)NNP*64;
    uint2* tabpack = (uint2*)(ws + off); off += (size_t)4*NB*64*2;
    float* wpc = ws + off; off += 4*64*112;
    float* pt  = ws + off; off += 100*112;
    float* s0Tp = ws + off; off += 4*4608;
    float* s1Tp = ws + off; off += 4*1280;
    float* s2Tp = ws + off; off += 4*640;
    float* wpTp = ws + off; off += 4*8064;
    float* zr  = ws + off; off += BB*176;
    float* rfall = acc;    // overlay: rfall consumed by pack_tab before agg writes acc

    prep_a<<<(NN + 255)/256, 256, 0, stream>>>(wp0, wp1, wp2, s0, s1, s2,
                                               wpc, s0Tp, s1Tp, s2Tp, deg);
    prep_b<<<(4*8064 + 255)/256, 256, 0, stream>>>(wpc, emb, wpTp, pt);

    hist_kernel<<<(EE + 255)/256, 256, 0, stream>>>(ei, deg);
    const int NSB = (NN + 255)/256;
    scan1<<<NSB, 256, 0, stream>>>(deg, startA, bsum);
    scan2<<<1, 256, 0, stream>>>(bsum, NSB);
    scan3<<<NSB, 256, 0, stream>>>(startA, bsum, cursor);
    geom_scatter<<<(EE + 255)/256, 256, 0, stream>>>(pos, ei, shift, cursor, edata);

    build_rf<<<4*(NB+1), 128, 0, stream>>>(rw1, rb1, rw2, rb2, rfall);
    pack_tab<<<(4*NB*64 + 255)/256, 256, 0, stream>>>(rfall, tabpack);
    init_hp32<<<NN, 256, 0, stream>>>(z, emb, pt, hG, Pa, Pb);

    unsigned* Pcur = Pa; unsigned* Pnxt = Pb;
    for (int L = 0; L < 4; L++) {
        int hasNext = (L < 3) ? 1 : 0;
        agg_kernel<<<NN/(WPB*2), 256, 0, stream>>>(
            Pcur, edata, startA, tabpack + (size_t)L*NB*64, acc);
        update_kernel<<<NNP/64, 256, 0, stream>>>(
            hG, acc, s0Tp + L*4608, s1Tp + L*1280, s2Tp + L*640,
            wpTp + (hasNext ? (L+1)*8064 : 0), Pnxt, hasNext);
        unsigned* tmp = Pcur; Pcur = Pnxt; Pnxt = tmp;
    }

    readout_ab<<<BB, 64, 0, stream>>>(hG, wq, wk, wv, zr);
    readout_c<<<BB, 128, 0, stream>>>(zr, m1, mb1, m2, mb2, (float*)d_out);
}

// Round 18
// 764.408 us; speedup vs baseline: 1.3707x; 1.3707x over previous
//
#include <hip/hip_runtime.h>
#include <hip/hip_bf16.h>
#include <hip/hip_fp16.h>

#define NN 50000
#define NNP 50048          // padded node count (782 * 64)
#define EE 800000
#define BB 1000
#define NB 2048            // radial table bins over [0, RTMAX]
#define RTMAX 10.0f
#define WPB 4              // waves per block in agg; each wave owns 2 nodes

typedef _Float16 half8 __attribute__((ext_vector_type(8)));
typedef float floatx4 __attribute__((ext_vector_type(4)));

__device__ __forceinline__ float silu(float x){ return x / (1.0f + __expf(-x)); }

// Internal channel layout (permuted vs reference):
//   scalar: ch j          = j            (j<64)
//   vector: ch 64+32d+j   = v[j][d]      (j<32, d<3)
//   tensor: ch 160+16e+j  = t[j][e]      (j<16, e<5)
// h stored f32 [NNP][256]; channels 240..255 stay zero (K-pad for MFMA).

// ---------------- prep_a: zero deg + wpc + s*Tp ----------------
__global__ __launch_bounds__(256) void prep_a(
    const float* __restrict__ wp0, const float* __restrict__ wp1, const float* __restrict__ wp2,
    const float* __restrict__ s0, const float* __restrict__ s1, const float* __restrict__ s2,
    float* __restrict__ wpc, float* __restrict__ s0Tp, float* __restrict__ s1Tp,
    float* __restrict__ s2Tp, int* __restrict__ deg)
{
    int t = blockIdx.x * 256 + threadIdx.x;
    if (t < NN) deg[t] = 0;
    if (t < 4*64*112) {
        int L = t / (64*112); int r = t % (64*112); int k = r / 112; int j = r % 112;
        float w;
        if (j < 64)      w = wp0[L*64*64 + k*64 + j];
        else if (j < 96) w = wp1[L*64*32 + k*32 + (j-64)];
        else             w = wp2[L*64*16 + k*16 + (j-96)];
        wpc[t] = w;
    }
    if (t < 4*64*72) {
        int L = t / 4608; int r = t % 4608; int j = r / 72; int k = r % 72;
        s0Tp[t] = (k < 64) ? s0[L*4096 + k*64 + j] : 0.0f;
    }
    if (t < 4*32*40) {
        int L = t / 1280; int r = t % 1280; int j = r / 40; int k = r % 40;
        s1Tp[t] = (k < 32) ? s1[L*1024 + k*32 + j] : 0.0f;
    }
    if (t < 4*16*40) {
        int L = t / 640; int r = t % 640; int j = r / 40; int k = r % 40;
        s2Tp[t] = (k < 16) ? s2[L*256 + k*16 + j] : 0.0f;
    }
}

// ---------------- prep_b: wpTp + pt ----------------
__global__ __launch_bounds__(256) void prep_b(
    const float* __restrict__ wpc, const float* __restrict__ emb,
    float* __restrict__ wpTp, float* __restrict__ pt)
{
    int t = blockIdx.x*256 + threadIdx.x;
    if (t < 4*112*72) {
        int L = t / 8064; int r = t % 8064; int m = r / 72; int k = r % 72;
        wpTp[t] = (k < 64) ? wpc[L*7168 + k*112 + m] : 0.0f;
    }
    if (t < 100*112) {
        int zz = t / 112, j = t % 112;
        float s = 0.0f;
        #pragma unroll 8
        for (int k = 0; k < 64; k++) s += emb[zz*64 + k] * wpc[k*112 + j];
        pt[t] = s;
    }
}

// ---------------- CSR build ----------------
__global__ __launch_bounds__(256) void hist_kernel(const int* __restrict__ ei, int* __restrict__ deg)
{
    int e = blockIdx.x * 256 + threadIdx.x;
    if (e < EE) atomicAdd(&deg[ei[EE + e]], 1);
}

__global__ __launch_bounds__(256) void scan1(const int* __restrict__ deg,
                                             int* __restrict__ start, int* __restrict__ bsum)
{
    __shared__ int buf[256];
    int tid = threadIdx.x;
    int i = blockIdx.x*256 + tid;
    int v = (i < NN) ? deg[i] : 0;
    buf[tid] = v; __syncthreads();
    #pragma unroll
    for (int off = 1; off < 256; off <<= 1) {
        int t = (tid >= off) ? buf[tid-off] : 0;
        __syncthreads(); buf[tid] += t; __syncthreads();
    }
    if (i < NN) start[i] = buf[tid] - v;
    if (tid == 255) bsum[blockIdx.x] = buf[255];
}
__global__ __launch_bounds__(256) void scan2(int* __restrict__ bsum, int nb)
{
    __shared__ int buf[256];
    int tid = threadIdx.x;
    int v = (tid < nb) ? bsum[tid] : 0;
    buf[tid] = v; __syncthreads();
    #pragma unroll
    for (int off = 1; off < 256; off <<= 1) {
        int t = (tid >= off) ? buf[tid-off] : 0;
        __syncthreads(); buf[tid] += t; __syncthreads();
    }
    if (tid < nb) bsum[tid] = buf[tid] - v;
}
__global__ __launch_bounds__(256) void scan3(int* __restrict__ start, const int* __restrict__ bsum,
                                             int* __restrict__ cursor)
{
    int i = blockIdx.x*256 + threadIdx.x;
    if (i < NN) { int v = start[i] + bsum[blockIdx.x]; start[i] = v; cursor[i] = v; }
    if (i == 0) start[NN] = EE;
}

// ---------------- fused geometry + scatter: 16B packed edge record ----------------
__global__ __launch_bounds__(256) void geom_scatter(
    const float* __restrict__ pos, const int* __restrict__ ei, const float* __restrict__ shift,
    int* __restrict__ cursor, int4* __restrict__ edata)
{
    int e = blockIdx.x * 256 + threadIdx.x;
    if (e >= EE) return;
    int s = ei[e], d = ei[EE + e];
    float vx = pos[d*3+0] - pos[s*3+0] + shift[e*3+0];
    float vy = pos[d*3+1] - pos[s*3+1] + shift[e*3+1];
    float vz = pos[d*3+2] - pos[s*3+2] + shift[e*3+2];
    float r = sqrtf(vx*vx + vy*vy + vz*vz);
    float inv = 1.0f / (r + 1e-9f);
    float x = vx*inv, y = vy*inv, z = vz*inv;
    int p = atomicAdd(&cursor[d], 1);
    __half2 xy = __floats2half2_rn(x, y);
    __half2 z0 = __floats2half2_rn(z, 0.0f);
    int4 rec;
    rec.x = s;
    rec.y = __float_as_int(r);
    rec.z = *(const int*)&xy;
    rec.w = *(const int*)&z0;
    edata[p] = rec;
}

// ---------------- radial features on the bin grid (f32, NB+1 bins) ----------------
__global__ __launch_bounds__(128) void build_rf(
    const float* __restrict__ rw1, const float* __restrict__ rb1,
    const float* __restrict__ rw2, const float* __restrict__ rb2,
    float* __restrict__ rfall)
{
    int idx = blockIdx.x;
    int L = idx / (NB+1), bin = idx % (NB+1);
    float r = bin * (RTMAX / NB);
    int t = threadIdx.x;
    __shared__ float h1[64];
    if (t < 64) {
        float s = rb1[L*64 + t];
        #pragma unroll
        for (int i = 0; i < 10; i++) { float a = 1.8f*r - (float)i; s += __expf(-a*a) * rw1[L*640 + i*64 + t]; }
        h1[t] = silu(s);
    }
    __syncthreads();
    if (t < 112) {
        float s = rb2[L*112 + t];
        #pragma unroll 8
        for (int k = 0; k < 64; k++) s += h1[k] * rw2[(size_t)L*7168 + k*112 + t];
        rfall[(size_t)idx*112 + t] = s * 0.25f;
    }
}

// pack (delta form): tabpack[L][bin][lane] = { half2(A_base,A_delta), half2(B_base,B_delta) }
__global__ __launch_bounds__(256) void pack_tab(
    const float* __restrict__ rfall, uint2* __restrict__ tabpack)
{
    int t = blockIdx.x*256 + threadIdx.x;
    if (t >= 4*NB*64) return;
    int lane = t & 63;
    int rest = t >> 6;
    int L = rest / NB, bin = rest % NB;
    const float* lo = rfall + (size_t)(L*(NB+1) + bin)*112;
    const float* hi = lo + 112;
    float aLo = lo[lane], aHi = hi[lane];
    float bLo = (lane < 48) ? lo[64+lane] : 0.0f;
    float bHi = (lane < 48) ? hi[64+lane] : 0.0f;
    __half2 ha = __floats2half2_rn(aLo, aHi - aLo);
    __half2 hb = __floats2half2_rn(bLo, bHi - bLo);
    uint2 o;
    o.x = *(const unsigned*)&ha;
    o.y = *(const unsigned*)&hb;
    tabpack[t] = o;
}

// ---------------- init: h f32 [NNP][256] + packed P0 ----------------
__global__ __launch_bounds__(256) void init_hp32(
    const int* __restrict__ z, const float* __restrict__ emb,
    const float* __restrict__ pt, float* __restrict__ hG, unsigned* __restrict__ Ppack)
{
    int n = blockIdx.x; int j = threadIdx.x;
    int zz = z[n];
    hG[(size_t)n*256 + j] = (j < 64) ? emb[zz*64 + j] : 0.0f;
    if (j < 64) {
        float a = pt[zz*112 + j];
        float b = (j < 48) ? pt[zz*112 + 64 + j] : 0.0f;
        __half2 hp = __floats2half2_rn(a, b);
        Ppack[(size_t)n*64 + j] = *(const unsigned*)&hp;
    }
}

// ---------------- aggregation: 2 nodes per wave; 12-float edge rows, b128 consume ----------------
// row: [boff, poff, fr, sh7 | sh0, sh1, sh2, 0 | sh3, sh4, sh5, sh6]
__global__ __launch_bounds__(256) void agg_kernel(
    const unsigned* __restrict__ Ppack, const int4* __restrict__ edata,
    const int* __restrict__ start, const uint2* __restrict__ tabp,
    float* __restrict__ acc)
{
    int lane = threadIdx.x & 63;
    int wv   = threadIdx.x >> 6;
    int nA = blockIdx.x*(WPB*2) + wv*2;
    int nB = nA + 1;

    __shared__ float ebuf_s[WPB][2][16*12];
    __shared__ float accb_s[WPB][2][240];

    int p0A = start[nA], p1A = start[nA+1];
    int p1B = start[nB+1];
    float aS_A = 0.0f, aS_B = 0.0f;
    float aB_A[5] = {0,0,0,0,0};
    float aB_B[5] = {0,0,0,0,0};
    bool hasB = lane < 48;
    bool isT  = lane >= 32;                  // tensor group (5 comps)
    int shqoff = isT ? 8 : 4;                // float offset of this group's sh quad
    const float binscale = (float)NB / RTMAX;
    const float C3 = 1.7320508075688772f, C15 = 3.872983346207417f, C5 = 2.23606797749979f;

    const char* tabc = (const char*)tabp;
    const char* Pc   = (const char*)Ppack;
    int lane8 = lane*8, lane4 = lane*4;

    int baseA = p0A, baseB = p1A;
    while (baseA < p1A || baseB < p1B) {
        int cntA = p1A - baseA; cntA = cntA < 0 ? 0 : (cntA > 16 ? 16 : cntA);
        int cntB = p1B - baseB; cntB = cntB < 0 ? 0 : (cntB > 16 ? 16 : cntB);
        #pragma unroll
        for (int s = 0; s < 2; s++) {
            int cnt  = s ? cntB : cntA;
            int base = s ? baseB : baseA;
            if (lane < cnt) {
                int4 rec = edata[base + lane];
                float f = fminf(__int_as_float(rec.y) * binscale, (float)NB - 0.5f);
                int b = (int)f;
                float fr = f - (float)b;
                __half2 xy = *(const __half2*)&rec.z;
                __half2 z0 = *(const __half2*)&rec.w;
                float x = __half2float(xy.x), y = __half2float(xy.y), z = __half2float(z0.x);
                float4* v4 = (float4*)(ebuf_s[wv][s] + lane*12);
                v4[0] = make_float4(__int_as_float(b*512), __int_as_float(rec.x*256), fr,
                                    0.5f*C15*(x*x - y*y));
                v4[1] = make_float4(C3*x, C3*y, C3*z, 0.0f);
                v4[2] = make_float4(C15*x*y, C15*y*z, 0.5f*C5*(3.0f*z*z - 1.0f), C15*x*z);
            }
        }
        asm volatile("s_waitcnt lgkmcnt(0)" ::: "memory");
        #pragma unroll
        for (int s = 0; s < 2; s++) {
            int cnt = s ? cntB : cntA;
            const float* eb = ebuf_s[wv][s];
            float aS_l = 0.0f;
            float aB_l[5] = {0,0,0,0,0};
            #pragma unroll 4
            for (int e = 0; e < 16; e++) {
                if (e < cnt) {
                    const float* ep = eb + e*12;
                    float4 md = *(const float4*)ep;                    // b128
                    int boff = __float_as_int(md.x);
                    int poff = __float_as_int(md.y);
                    float fr = md.z;
                    uint2 tt = *(const uint2*)(tabc + boff + lane8);
                    unsigned pv = *(const unsigned*)(Pc + poff + lane4);
                    __half2 ha = *(const __half2*)&tt.x;
                    __half2 hp = *(const __half2*)&pv;
                    float rfA = __half2float(ha.x) + __half2float(ha.y)*fr;
                    aS_l += rfA * __half2float(hp.x);
                    if (hasB) {
                        float4 sq = *(const float4*)(ep + shqoff);     // b128
                        __half2 hb = *(const __half2*)&tt.y;
                        float rfB = __half2float(hb.x) + __half2float(hb.y)*fr;
                        float msg = rfB * __half2float(hp.y);
                        aB_l[0] += msg * sq.x;
                        aB_l[1] += msg * sq.y;
                        aB_l[2] += msg * sq.z;
                        if (isT) { aB_l[3] += msg * sq.w; aB_l[4] += msg * md.w; }
                    }
                }
            }
            if (s == 0) {
                aS_A += aS_l;
                #pragma unroll
                for (int d = 0; d < 5; d++) aB_A[d] += aB_l[d];
            } else {
                aS_B += aS_l;
                #pragma unroll
                for (int d = 0; d < 5; d++) aB_B[d] += aB_l[d];
            }
        }
        asm volatile("s_waitcnt lgkmcnt(0)" ::: "memory");
        baseA += 16; baseB += 16;
    }

    // stage into LDS in PERMUTED channel layout
    #pragma unroll
    for (int s = 0; s < 2; s++) {
        float* ab = accb_s[wv][s];
        ab[lane] = s ? aS_B : aS_A;
        const float* aB = s ? aB_B : aB_A;
        if (lane < 32) {
            #pragma unroll
            for (int d = 0; d < 3; d++) ab[64 + 32*d + lane] = aB[d];
        } else if (lane < 48) {
            #pragma unroll
            for (int d = 0; d < 5; d++) ab[160 + 16*d + (lane-32)] = aB[d];
        }
    }
    asm volatile("s_waitcnt lgkmcnt(0)" ::: "memory");
    #pragma unroll
    for (int s = 0; s < 2; s++) {
        float* arow = acc + (size_t)(nA + s)*240;
        const float* ab = accb_s[wv][s];
        #pragma unroll
        for (int c = lane; c < 240; c += 64) arow[c] = ab[c];
    }
}

// ---------------- MFMA node update + projection (h stays f32) ----------------
__global__ __launch_bounds__(256) void update_kernel(
    float* __restrict__ hG, const float* __restrict__ acc,
    const float* __restrict__ s0Tp, const float* __restrict__ s1Tp, const float* __restrict__ s2Tp,
    const float* __restrict__ wpTp, unsigned* __restrict__ Pnext, int hasNext)
{
    __shared__ _Float16 w0[64*72];
    __shared__ _Float16 w1[32*40];
    __shared__ _Float16 w2[16*40];
    __shared__ _Float16 wpl[112*72];
    __shared__ _Float16 sn[64*72];
    __shared__ _Float16 pbuf[64*120];

    int tid = threadIdx.x;
    int lane = tid & 63, wv = tid >> 6;
    int m = lane & 15, quad = lane >> 4;
    int nblk0 = blockIdx.x * 64;
    int n0 = nblk0 + wv*16;

    for (int i = tid; i < 64*72; i += 256) w0[i] = (_Float16)s0Tp[i];
    for (int i = tid; i < 32*40; i += 256) w1[i] = (_Float16)s1Tp[i];
    for (int i = tid; i < 16*40; i += 256) w2[i] = (_Float16)s2Tp[i];
    for (int i = tid; i < 112*72; i += 256) wpl[i] = (_Float16)wpTp[i];
    __syncthreads();

    size_t hrowm = (size_t)(n0 + m)*256;
    size_t arow0 = (size_t)(n0 + quad*4)*240;
    size_t orow0 = (size_t)(n0 + quad*4)*256;

#define LD8(OFF) ({ \
        float4 v0_ = *(const float4*)(hG + (OFF)); \
        float4 v1_ = *(const float4*)(hG + (OFF) + 4); \
        half8 h_; \
        h_[0] = (_Float16)v0_.x; h_[1] = (_Float16)v0_.y; \
        h_[2] = (_Float16)v0_.z; h_[3] = (_Float16)v0_.w; \
        h_[4] = (_Float16)v1_.x; h_[5] = (_Float16)v1_.y; \
        h_[6] = (_Float16)v1_.z; h_[7] = (_Float16)v1_.w; h_; })

    // ---- GEMM0: scalar block (cols 0..63, K 0..63) ----
    {
        half8 a0 = LD8(hrowm + 0  + quad*8);
        half8 a1 = LD8(hrowm + 32 + quad*8);
        #pragma unroll
        for (int t = 0; t < 4; t++) {
            int cb = 16*t;
            floatx4 c;
            #pragma unroll
            for (int r = 0; r < 4; r++) c[r] = acc[arow0 + (size_t)r*240 + cb + m];
            c = __builtin_amdgcn_mfma_f32_16x16x32_f16(a0, *(const half8*)&w0[(cb+m)*72 + 0  + quad*8], c, 0, 0, 0);
            c = __builtin_amdgcn_mfma_f32_16x16x32_f16(a1, *(const half8*)&w0[(cb+m)*72 + 32 + quad*8], c, 0, 0, 0);
            #pragma unroll
            for (int r = 0; r < 4; r++) {
                float u = silu(c[r]);
                hG[orow0 + (size_t)r*256 + cb + m] = u;
                sn[(wv*16 + quad*4 + r)*72 + cb + m] = (_Float16)u;
            }
        }
    }
    // ---- GEMM1: vector blocks d=0..2 ----
    #pragma unroll
    for (int d = 0; d < 3; d++) {
        int kb = 64 + 32*d;
        half8 av = LD8(hrowm + kb + quad*8);
        #pragma unroll
        for (int t = 0; t < 2; t++) {
            int cb = kb + 16*t;
            floatx4 c;
            #pragma unroll
            for (int r = 0; r < 4; r++) c[r] = acc[arow0 + (size_t)r*240 + cb + m];
            c = __builtin_amdgcn_mfma_f32_16x16x32_f16(av, *(const half8*)&w1[(16*t+m)*40 + quad*8], c, 0, 0, 0);
            #pragma unroll
            for (int r = 0; r < 4; r++) hG[orow0 + (size_t)r*256 + cb + m] = c[r];
        }
    }
    // ---- GEMM2: tensor blocks e=0..4 ----
    #pragma unroll
    for (int e = 0; e < 5; e++) {
        int kb = 160 + 16*e;
        half8 at_ = LD8(hrowm + kb + quad*8);
        floatx4 c;
        #pragma unroll
        for (int r = 0; r < 4; r++) c[r] = acc[arow0 + (size_t)r*240 + kb + m];
        c = __builtin_amdgcn_mfma_f32_16x16x32_f16(at_, *(const half8*)&w2[m*40 + quad*8], c, 0, 0, 0);
        #pragma unroll
        for (int r = 0; r < 4; r++) hG[orow0 + (size_t)r*256 + kb + m] = c[r];
    }

    // ---- projection P = s_new @ wpc_next ----
    if (hasNext) {
        asm volatile("s_waitcnt lgkmcnt(0)" ::: "memory");
        half8 p0 = *(const half8*)&sn[(wv*16 + m)*72 + 0  + quad*8];
        half8 p1 = *(const half8*)&sn[(wv*16 + m)*72 + 32 + quad*8];
        #pragma unroll
        for (int t = 0; t < 7; t++) {
            floatx4 c = {0.0f, 0.0f, 0.0f, 0.0f};
            c = __builtin_amdgcn_mfma_f32_16x16x32_f16(p0, *(const half8*)&wpl[(16*t+m)*72 + 0  + quad*8], c, 0, 0, 0);
            c = __builtin_amdgcn_mfma_f32_16x16x32_f16(p1, *(const half8*)&wpl[(16*t+m)*72 + 32 + quad*8], c, 0, 0, 0);
            #pragma unroll
            for (int r = 0; r < 4; r++) pbuf[(wv*16 + quad*4 + r)*120 + 16*t + m] = (_Float16)c[r];
        }
        __syncthreads();
        for (int i = tid; i < 64*64; i += 256) {
            int node = i >> 6, j = i & 63;
            _Float16 aa = pbuf[node*120 + j];
            _Float16 bb = (j < 48) ? pbuf[node*120 + 64 + j] : (_Float16)0.0f;
            unsigned lo = *(const unsigned short*)&aa;
            unsigned hi = *(const unsigned short*)&bb;
            if (nblk0 + node < NN) Pnext[(size_t)(nblk0 + node)*64 + j] = lo | (hi << 16);
        }
    }
#undef LD8
}

// ---------------- merged readout A+B (kq is block-local) ----------------
__global__ __launch_bounds__(64) void readout_ab(
    const float* __restrict__ hG, const float* __restrict__ wq, const float* __restrict__ wk,
    const float* __restrict__ wv, float* __restrict__ zr)
{
    int b = blockIdx.x; int j = threadIdx.x;
    int na = 50 * b;
    const float* hr = hG + (size_t)na*256;
    __shared__ float sa[64], qv[64], kqv[64];
    __shared__ float hblk[64][51];
    __shared__ float at[64], hbar[64];
    sa[j] = hr[j];
    if (j < 50) {
        const float* hrr = hG + (size_t)(50*b + j)*256;
        #pragma unroll 8
        for (int k = 0; k < 64; k++) hblk[k][j] = hrr[k];
    }
    __syncthreads();
    float q = 0.0f;
    #pragma unroll 8
    for (int k = 0; k < 64; k++) q += sa[k] * wq[k*64 + j];
    qv[j] = q;
    zr[b*176 + j] = sa[j];
    if (j < 32) {
        float nv = 0.0f;
        #pragma unroll
        for (int c = 0; c < 3; c++) { float v = hr[64 + 32*c + j]; nv += v*v; }
        zr[b*176 + 128 + j] = nv;
    }
    if (j < 16) {
        float nt = 0.0f;
        #pragma unroll
        for (int c = 0; c < 5; c++) { float v = hr[160 + 16*c + j]; nt += v*v; }
        zr[b*176 + 160 + j] = nt;
    }
    __syncthreads();
    float s = 0.0f;
    #pragma unroll 8
    for (int jj = 0; jj < 64; jj++) s += wk[j*64 + jj] * qv[jj];
    kqv[j] = s;
    __syncthreads();
    float logit = -1e30f;
    if (j < 50) {
        float t = 0.0f;
        #pragma unroll 8
        for (int k = 0; k < 64; k++) t += hblk[k][j] * kqv[k];
        logit = t * 0.125f;
    }
    float mx = logit;
    for (int o = 32; o; o >>= 1) mx = fmaxf(mx, __shfl_xor(mx, o));
    float ex = (j < 50) ? __expf(logit - mx) : 0.0f;
    float den = ex;
    for (int o = 32; o; o >>= 1) den += __shfl_xor(den, o);
    at[j] = ex / den;
    __syncthreads();
    float hb = 0.0f;
    #pragma unroll 1
    for (int i = 0; i < 50; i++) hb += at[i] * hblk[j][i];
    hbar[j] = hb;
    __syncthreads();
    float c = 0.0f;
    #pragma unroll 8
    for (int k = 0; k < 64; k++) c += hbar[k] * wv[k*64 + j];
    zr[b*176 + 64 + j] = c;
}

// ---------------- readout C ----------------
__global__ __launch_bounds__(128) void readout_c(
    const float* __restrict__ zr, const float* __restrict__ m1, const float* __restrict__ mb1,
    const float* __restrict__ m2, const float* __restrict__ mb2, float* __restrict__ out)
{
    int b = blockIdx.x; int j = threadIdx.x;
    __shared__ float z[176], tb[128];
    for (int t = j; t < 176; t += 128) z[t] = zr[b*176 + t];
    __syncthreads();
    float a = mb1[j];
    #pragma unroll 8
    for (int k = 0; k < 176; k++) a += z[k] * m1[k*128 + j];
    tb[j] = silu(a);
    __syncthreads();
    float o = mb2[j];
    #pragma unroll 8
    for (int k = 0; k < 128; k++) o += tb[k] * m2[k*128 + j];
    out[b*128 + j] = o;
}

extern "C" void kernel_launch(void* const* d_in, const int* in_sizes, int n_in,
                              void* d_out, int out_size, void* d_ws, size_t ws_size,
                              hipStream_t stream)
{
    const int*   z     = (const int*)  d_in[0];
    const float* pos   = (const float*)d_in[1];
    const int*   ei    = (const int*)  d_in[2];
    const float* shift = (const float*)d_in[3];
    const float* emb = (const float*)d_in[6];
    const float* rw1 = (const float*)d_in[7];
    const float* rb1 = (const float*)d_in[8];
    const float* rw2 = (const float*)d_in[9];
    const float* rb2 = (const float*)d_in[10];
    const float* wp0 = (const float*)d_in[11];
    const float* wp1 = (const float*)d_in[12];
    const float* wp2 = (const float*)d_in[13];
    const float* s0  = (const float*)d_in[14];
    const float* s1  = (const float*)d_in[15];
    const float* s2  = (const float*)d_in[16];
    const float* wq  = (const float*)d_in[17];
    const float* wk  = (const float*)d_in[18];
    const float* wv  = (const float*)d_in[19];
    const float* m1  = (const float*)d_in[20];
    const float* mb1 = (const float*)d_in[21];
    const float* m2  = (const float*)d_in[22];
    const float* mb2 = (const float*)d_in[23];

    float* ws = (float*)d_ws;
    size_t off = 0;
    int4*  edata = (int4*)(ws + off); off += (size_t)4*EE;
    int*   deg    = (int*)(ws + off); off += NN;
    int*   startA = (int*)(ws + off); off += NN + 4;
    int*   cursor = (int*)(ws + off); off += NN;
    int*   bsum   = (int*)(ws + off); off += 256;
    float* hG  = ws + off; off += (size_t)NNP*256;   // f32 [NNP][256]
    float* acc = ws + off; off += (size_t)NNP*240;
    unsigned* Pa = (unsigned*)(ws + off); off += (size_t)NNP*64;
    unsigned* Pb = (unsigned*)(ws + off); off += (size_t)NNP*64;
    uint2* tabpack = (uint2*)(ws + off); off += (size_t)4*NB*64*2;
    float* wpc = ws + off; off += 4*64*112;
    float* pt  = ws + off; off += 100*112;
    float* s0Tp = ws + off; off += 4*4608;
    float* s1Tp = ws + off; off += 4*1280;
    float* s2Tp = ws + off; off += 4*640;
    float* wpTp = ws + off; off += 4*8064;
    float* zr  = ws + off; off += BB*176;
    float* rfall = acc;    // overlay: rfall consumed by pack_tab before agg writes acc

    prep_a<<<(NN + 255)/256, 256, 0, stream>>>(wp0, wp1, wp2, s0, s1, s2,
                                               wpc, s0Tp, s1Tp, s2Tp, deg);
    prep_b<<<(4*8064 + 255)/256, 256, 0, stream>>>(wpc, emb, wpTp, pt);

    hist_kernel<<<(EE + 255)/256, 256, 0, stream>>>(ei, deg);
    const int NSB = (NN + 255)/256;
    scan1<<<NSB, 256, 0, stream>>>(deg, startA, bsum);
    scan2<<<1, 256, 0, stream>>>(bsum, NSB);
    scan3<<<NSB, 256, 0, stream>>>(startA, bsum, cursor);
    geom_scatter<<<(EE + 255)/256, 256, 0, stream>>>(pos, ei, shift, cursor, edata);

    build_rf<<<4*(NB+1), 128, 0, stream>>>(rw1, rb1, rw2, rb2, rfall);
    pack_tab<<<(4*NB*64 + 255)/256, 256, 0, stream>>>(rfall, tabpack);
    init_hp32<<<NN, 256, 0, stream>>>(z, emb, pt, hG, Pa);

    unsigned* Pcur = Pa; unsigned* Pnxt = Pb;
    for (int L = 0; L < 4; L++) {
        int hasNext = (L < 3) ? 1 : 0;
        agg_kernel<<<NN/(WPB*2), 256, 0, stream>>>(
            Pcur, edata, startA, tabpack + (size_t)L*NB*64, acc);
        update_kernel<<<NNP/64, 256, 0, stream>>>(
            hG, acc, s0Tp + L*4608, s1Tp + L*1280, s2Tp + L*640,
            wpTp + (hasNext ? (L+1)*8064 : 0), Pnxt, hasNext);
        unsigned* tmp = Pcur; Pcur = Pnxt; Pnxt = tmp;
    }

    readout_ab<<<BB, 64, 0, stream>>>(hG, wq, wk, wv, zr);
    readout_c<<<BB, 128, 0, stream>>>(zr, m1, mb1, m2, mb2, (float*)d_out);
}